// Round 10
// baseline (155.251 us; speedup 1.0000x reference)
//
#include <hip/hip_runtime.h>
#include <hip/hip_bf16.h>
#include <math.h>

// Problem constants
constexpr int kB  = 2;
constexpr int kS  = 256;
constexpr int kH  = 8;
constexpr float kEPS = 1e-5f;

// Output offsets (floats) in d_out, in reference return order
constexpr int OFF_EST = 0;                         // (B,2,S,DV,H)   524288
constexpr int OFF_OUT = 524288;                    // (B,2,S,DE)     524288
constexpr int OFF_QIJ = 1048576;                   // (B,2,S,S,H)    2097152
constexpr int OFF_ZIJ = 3145728;                   // (B,2,S,S,DT)   134217728
constexpr int OFF_EPO = 137363456;                 // (2,512,1)      1024

// Workspace offsets (floats)
constexpr int WS_EFR = 0;          // (S,DT)
constexpr int WS_EFI = 131072;
constexpr int WS_EBR = 262144;     // reused later as A2P (bf16, 1 MB spans EBR+EBI)
constexpr int WS_EBI = 393216;
constexpr int WS_UQR = 524288;     // (B,H,S,DV)
constexpr int WS_UQI = 786432;
constexpr int WS_UKR = 1048576;    // (B,H,DV,S)  transposed
constexpr int WS_UKI = 1310720;
constexpr int WS_UVR = 1572864;    // (B,H,S,DV)
constexpr int WS_UVI = 1835008;
constexpr int WS_VR  = 2097152;    // (B,S,DV,H)
constexpr int WS_VI  = 2359296;
constexpr int WS_BF  = 3145728;    // bf16 region base (float offset)

// bf16-element offsets within bf16 region
constexpr int A2Q = 0;             // [512][1024]
constexpr int A2K = 524288;
constexpr int A2V = 1048576;
constexpr int B2R0 = 1572864;      // B2R(z) = B2R0 + z*1048576; B2I = +524288

typedef __attribute__((ext_vector_type(8))) short bf16x8;
typedef __attribute__((ext_vector_type(4))) float f32x4;
typedef __attribute__((ext_vector_type(8))) unsigned short u16x8;
typedef __attribute__((ext_vector_type(4))) unsigned short u16x4;

__device__ __forceinline__ float sigm(float x) { return 1.f / (1.f + expf(-x)); }
__device__ __forceinline__ unsigned short f2b(float f) {
    __hip_bfloat16 h = __float2bfloat16(f);
    return *reinterpret_cast<unsigned short*>(&h);
}

// ---------------------------------------------------------------------------
// Kernel 1 (fused prep): blocks 0..511 ef/eb+epoch, 512..1279 convA,
// 1280..1791 convW. (Round-4 version; work-identical to the 3 separate
// kernels, 2 fewer launches.)
// ---------------------------------------------------------------------------
__global__ __launch_bounds__(256) void k_prep(
    const float* __restrict__ tall, const float* __restrict__ Lim,
    const float* __restrict__ Lre,
    const float* __restrict__ zq, const float* __restrict__ zk,
    const float* __restrict__ zv,
    const float* __restrict__ wq, const float* __restrict__ wk,
    const float* __restrict__ wv, const float* __restrict__ wp,
    float* __restrict__ efr, float* __restrict__ efi,
    float* __restrict__ ebr, float* __restrict__ ebi,
    float* __restrict__ epo, __hip_bfloat16* __restrict__ bfbase)
{
    __shared__ float s0[64][65];
    __shared__ float s1[64][65];
    const int bid = blockIdx.x;
    const int tid = threadIdx.x;

    if (bid < 512) {
        // ---- ef/eb precompute ----
        int idx = bid * 256 + tid;
        int s = idx >> 9;
        int c = idx & 511;
        int h = c >> 6;
        int d = c & 63;
        float li = (d < 32) ? Lim[h * 32 + d] : -Lim[h * 32 + d - 32];
        float lr = Lre[h];
        float t  = tall[s] / (tall[kS - 1] - tall[0]);
        float ph  = t * li;
        float mag = expf(t * lr);
        float cp  = cosf(ph);
        float sp  = sinf(ph);
        efr[idx] = mag * cp;
        efi[idx] = mag * sp;
        ebr[idx] = cp / mag;
        ebi[idx] = -sp / mag;
        if (s == 0) {
            epo[c]       = lr;
            epo[512 + c] = li;
        }
    } else if (bid < 1280) {
        // ---- convA: Zq/Zk/Zv -> bf16 [512][1024] ----
        int idx = (bid - 512) * 256 + tid;
        int tz  = idx >> 16;
        int rem = idx & 65535;
        int m   = rem >> 7;
        int k0  = (rem & 127) * 8;
        const float* src = (tz == 0) ? zq : (tz == 1) ? zk : zv;
        int b = m >> 8, s = m & 255;
        int c = (k0 >= 512) ? 1 : 0;
        int e = k0 - c * 512;
        const float* p = src + ((b * 2 + c) * 256 + s) * 512 + e;
        float4 v0 = *(const float4*)p;
        float4 v1 = *(const float4*)(p + 4);
        u16x8 o;
        o[0] = f2b(v0.x); o[1] = f2b(v0.y); o[2] = f2b(v0.z); o[3] = f2b(v0.w);
        o[4] = f2b(v1.x); o[5] = f2b(v1.y); o[6] = f2b(v1.z); o[7] = f2b(v1.w);
        __hip_bfloat16* dst = bfbase + ((tz == 0) ? A2Q : (tz == 1) ? A2K : A2V)
                              + m * 1024 + k0;
        *(u16x8*)dst = o;
    } else {
        // ---- convW: weights -> bf16 [512 n][1024 k] transposed ----
        int wid = bid - 1280;
        int z = wid >> 7;
        int r2 = wid & 127;
        int k0 = (r2 & 15) * 64;
        int n0 = (r2 >> 4) * 64;
        const float* W  = (z == 0) ? wq : (z == 1) ? wk : (z == 2) ? wv : wp;
        const float* W0 = W;
        const float* W1 = W + 262144;
        const int kp = k0 & 511;
        const bool hf = (k0 >= 512);
        const int r = tid >> 2;
        const int q = tid & 3;
#pragma unroll
        for (int c = 0; c < 4; ++c) {
            int col = q * 16 + c * 4;
            *(float4*)&s0[r][col] = *(const float4*)&W0[(kp + r) * 512 + n0 + col];
            *(float4*)&s1[r][col] = *(const float4*)&W1[(kp + r) * 512 + n0 + col];
        }
        __syncthreads();
        u16x8 r0, r1, i0, i1;
#pragma unroll
        for (int u = 0; u < 8; ++u) {
            int kl = q * 16 + u;
            float w0 = s0[kl][r], w1 = s1[kl][r];
            r0[u] = f2b(hf ? -w1 : w0);
            i0[u] = f2b(hf ?  w0 : w1);
        }
#pragma unroll
        for (int u = 0; u < 8; ++u) {
            int kl = q * 16 + 8 + u;
            float w0 = s0[kl][r], w1 = s1[kl][r];
            r1[u] = f2b(hf ? -w1 : w0);
            i1[u] = f2b(hf ?  w0 : w1);
        }
        __hip_bfloat16* pr = bfbase + B2R0 + z * 1048576
                             + (size_t)(n0 + r) * 1024 + k0 + q * 16;
        __hip_bfloat16* pi = pr + 524288;
        *(u16x8*)pr       = r0;
        *(u16x8*)(pr + 8) = r1;
        *(u16x8*)pi       = i0;
        *(u16x8*)(pi + 8) = i1;
    }
}

// ---------------------------------------------------------------------------
// Kernel 2: MFMA complex GEMM for QKV (verified round-2/6 kernel)
// ---------------------------------------------------------------------------
__global__ __launch_bounds__(256) void k_cmfma_qkv(
    const __hip_bfloat16* __restrict__ bfbase,
    const float* __restrict__ bq, const float* __restrict__ bk,
    const float* __restrict__ bv,
    const float* __restrict__ ebr, const float* __restrict__ ebi,
    float* __restrict__ uqr, float* __restrict__ uqi,
    float* __restrict__ ukr, float* __restrict__ uki,
    float* __restrict__ uvr, float* __restrict__ uvi,
    float* __restrict__ vr,  float* __restrict__ vi)
{
    __shared__ __align__(16) char sm[24576];
    char* sA  = sm;
    char* sBr = sm + 8192;
    char* sBi = sm + 16384;

    const int mode = (int)blockIdx.z;
    const __hip_bfloat16* A2 = bfbase + ((mode == 0) ? A2Q : (mode == 1) ? A2K : A2V);
    const __hip_bfloat16* Br = bfbase + B2R0 + mode * 1048576;
    const __hip_bfloat16* Bi = Br + 524288;
    const float* bias = (mode == 0) ? bq : (mode == 1) ? bk : bv;

    const int tid = threadIdx.x;
    const int m0 = blockIdx.y * 64;
    const int n0 = blockIdx.x * 64;
    const int lane = tid & 63;
    const int wv2 = tid >> 6;
    const int wr = wv2 >> 1, wc = wv2 & 1;
    const int lx = lane & 15, lhi = lane >> 4;

    const int srow  = tid >> 2;
    const int sslot = (tid & 3) * 32;

    const char* gA  = (const char*)(A2 + (size_t)(m0 + srow) * 1024);
    const char* gBr = (const char*)(Br + (size_t)(n0 + srow) * 1024);
    const char* gBi = (const char*)(Bi + (size_t)(n0 + srow) * 1024);
    const int swz = (srow & 7) << 4;
    char* dA  = sA  + srow * 128;
    char* dBr = sBr + srow * 128;
    char* dBi = sBi + srow * 128;

    f32x4 accR[2][2] = {};
    f32x4 accI[2][2] = {};

    int rowA[2], rowB[2];
    rowA[0] = wr * 32 + lx;  rowA[1] = rowA[0] + 16;
    rowB[0] = wc * 32 + lx;  rowB[1] = rowB[0] + 16;

    for (int kt = 0; kt < 16; ++kt) {
        const int kb = kt * 128;
        {
            float4 a0 = *(const float4*)(gA  + kb + sslot);
            float4 a1 = *(const float4*)(gA  + kb + sslot + 16);
            float4 b0 = *(const float4*)(gBr + kb + sslot);
            float4 b1 = *(const float4*)(gBr + kb + sslot + 16);
            float4 c0 = *(const float4*)(gBi + kb + sslot);
            float4 c1 = *(const float4*)(gBi + kb + sslot + 16);
            *(float4*)(dA  + ( sslot       ^ swz)) = a0;
            *(float4*)(dA  + ((sslot + 16) ^ swz)) = a1;
            *(float4*)(dBr + ( sslot       ^ swz)) = b0;
            *(float4*)(dBr + ((sslot + 16) ^ swz)) = b1;
            *(float4*)(dBi + ( sslot       ^ swz)) = c0;
            *(float4*)(dBi + ((sslot + 16) ^ swz)) = c1;
        }
        __syncthreads();
#pragma unroll
        for (int kk = 0; kk < 2; ++kk) {
            const int kbyte = kk * 64 + lhi * 16;
            bf16x8 af[2], brf[2], bif[2];
#pragma unroll
            for (int x = 0; x < 2; ++x) {
                int ra = rowA[x];
                af[x]  = *(const bf16x8*)(sA  + ra * 128 + (kbyte ^ ((ra & 7) << 4)));
                int rb = rowB[x];
                brf[x] = *(const bf16x8*)(sBr + rb * 128 + (kbyte ^ ((rb & 7) << 4)));
                bif[x] = *(const bf16x8*)(sBi + rb * 128 + (kbyte ^ ((rb & 7) << 4)));
            }
#pragma unroll
            for (int a = 0; a < 2; ++a)
#pragma unroll
                for (int bb = 0; bb < 2; ++bb) {
                    accR[a][bb] = __builtin_amdgcn_mfma_f32_16x16x32_bf16(
                        af[a], brf[bb], accR[a][bb], 0, 0, 0);
                    accI[a][bb] = __builtin_amdgcn_mfma_f32_16x16x32_bf16(
                        af[a], bif[bb], accI[a][bb], 0, 0, 0);
                }
        }
        __syncthreads();
    }

#pragma unroll
    for (int a = 0; a < 2; ++a) {
#pragma unroll
        for (int bb = 0; bb < 2; ++bb) {
#pragma unroll
            for (int j = 0; j < 4; ++j) {
                int m = m0 + wr * 32 + a * 16 + lhi * 4 + j;
                int n = n0 + wc * 32 + bb * 16 + lx;
                float yr = accR[a][bb][j] + bias[n];
                float yi = accI[a][bb][j] + bias[512 + n];
                int b = m >> 8, s = m & 255;
                int h = n >> 6, d = n & 63;
                float er_ = ebr[s * 512 + n], ei_ = ebi[s * 512 + n];
                float ur = er_ * yr - ei_ * yi;
                float ui = er_ * yi + ei_ * yr;
                if (mode == 0) {
                    int idx = ((b * 8 + h) * 256 + s) * 64 + d;
                    uqr[idx] = ur; uqi[idx] = ui;
                } else if (mode == 1) {
                    int idx = ((b * 8 + h) * 64 + d) * 256 + s;
                    ukr[idx] = ur; uki[idx] = ui;
                } else {
                    int idx = ((b * 8 + h) * 256 + s) * 64 + d;
                    uvr[idx] = ur; uvi[idx] = ui;
                    int vidx = (b * 256 + s) * 512 + d * 8 + h;
                    vr[vidx] = yr; vi[vidx] = yi;
                }
            }
        }
    }
}

// ---------------------------------------------------------------------------
// Kernel 3 (launch A): blocks 0..127 = scores+softmax+PV+est (round-9
// verified); blocks 128..16511 = Z_ij b=0 half (verified scalar NT stores).
// ---------------------------------------------------------------------------
__global__ __launch_bounds__(256) void k_zij_attn(
    const float* __restrict__ efr, const float* __restrict__ efi,
    const float* __restrict__ uvr, const float* __restrict__ uvi,
    float* __restrict__ zout,
    const float* __restrict__ uqr, const float* __restrict__ uqi,
    const float* __restrict__ ukr, const float* __restrict__ uki,
    const float* __restrict__ tall,
    const float* __restrict__ Lre, const float* __restrict__ Lom,
    const float* __restrict__ Lga, const float* __restrict__ NF,
    const float* __restrict__ TAU,
    float* __restrict__ qij,
    const float* __restrict__ vr,  const float* __restrict__ vi,
    const float* __restrict__ ETA,
    float* __restrict__ out_est, __hip_bfloat16* __restrict__ a2p)
{
    __shared__ __align__(16) char smem[66688];
    float (*sP)[257] = (float(*)[257])smem;
    float (*sKr)[32] = (float(*)[32])(smem + 32896);
    float (*sKi)[32] = (float(*)[32])(smem + 41088);
    float (*sQr)[68] = (float(*)[68])(smem + 49280);
    float (*sQi)[68] = (float(*)[68])(smem + 57984);
    float (*sVr)[64] = (float(*)[64])(smem + 32896);
    float (*sVi)[64] = (float(*)[64])(smem + 41088);

    const int bid = blockIdx.x;
    const int tid = threadIdx.x;

    if (bid >= 128) {
        // ---------------- Z_ij path, b = 0 ----------------
        const int z  = bid - 128;
        const int j0 = (z & 63) * 4;
        const int i  = z >> 6;        // 0..255
        const int b  = 0;
#pragma unroll
        for (int half = 0; half < 2; half++) {
            int dt = half * 256 + tid;
            float fr = efr[i * 512 + dt];
            float fi = efi[i * 512 + dt];
            int h = dt >> 6, d = dt & 63;
            const float* ur = uvr + ((b * 8 + h) * 256) * 64 + d;
            const float* ui = uvi + ((b * 8 + h) * 256) * 64 + d;
#pragma unroll
            for (int jj = 0; jj < 4; jj++) {
                int j = j0 + jj;
                float vr_ = ur[j * 64];
                float vi_ = ui[j * 64];
                float zr = fr * vr_ - fi * vi_;
                float zi = fr * vi_ + fi * vr_;
                int idx0 = (b * 2) * 33554432 + i * 131072 + j * 512 + dt;
                __builtin_nontemporal_store(zr, &zout[idx0]);
                __builtin_nontemporal_store(zi, &zout[idx0 + 33554432]);
            }
        }
        return;
    }

    // ------------- attn path: scores + softmax + PV + est -------------
    const int it = bid & 7;
    const int h  = (bid >> 3) & 7;
    const int b  = bid >> 6;
    const int i0 = it * 32;
    const int ti = tid >> 3;
    const int tj = tid & 7;
    const int i  = i0 + ti;

    {
        const float* qsr = uqr + ((b * 8 + h) * 256 + i) * 64;
        const float* qsi = uqi + ((b * 8 + h) * 256 + i) * 64;
        *(float4*)&sQr[ti][tj * 4]      = *(const float4*)&qsr[tj * 4];
        *(float4*)&sQr[ti][32 + tj * 4] = *(const float4*)&qsr[32 + tj * 4];
        *(float4*)&sQi[ti][tj * 4]      = *(const float4*)&qsi[tj * 4];
        *(float4*)&sQi[ti][32 + tj * 4] = *(const float4*)&qsi[32 + tj * 4];
    }

    const float lre  = Lre[h];
    const float om   = Lom[h] * Lom[h];
    const float ga   = Lga[h] * Lga[h] + kEPS;
    const float nf2  = NF[h] * NF[h] + kEPS;
    const float tau2 = TAU[h] * TAU[h];
    const float den  = 2.f * lre;
    const float invT = 1.f / (tall[kS - 1] - tall[0]);
    const float t_i  = tall[i] * invT;
    const float m2i  = expf(2.f * t_i * lre);
    const bool  denok = fabsf(den) > 1e-6f;

    const int kr2 = tid >> 2;
    const int kq2 = tid & 3;

    for (int jt = 0; jt <= it; ++jt) {
        const int j0 = jt * 32;
        __syncthreads();
        {
            const float* ksrc_r = ukr + ((b * 8 + h) * 64 + kr2) * 256 + j0;
            const float* ksrc_i = uki + ((b * 8 + h) * 64 + kr2) * 256 + j0;
            *(float4*)&sKr[kr2][kq2 * 4]      = *(const float4*)&ksrc_r[kq2 * 4];
            *(float4*)&sKr[kr2][16 + kq2 * 4] = *(const float4*)&ksrc_r[16 + kq2 * 4];
            *(float4*)&sKi[kr2][kq2 * 4]      = *(const float4*)&ksrc_i[kq2 * 4];
            *(float4*)&sKi[kr2][16 + kq2 * 4] = *(const float4*)&ksrc_i[16 + kq2 * 4];
        }
        __syncthreads();

        float acc[4] = {0.f, 0.f, 0.f, 0.f};
#pragma unroll 16
        for (int d = 0; d < 64; d++) {
            float qr = sQr[ti][d];
            float qi = sQi[ti][d];
            float4 kr = *(float4*)&sKr[d][tj * 4];
            float4 ki = *(float4*)&sKi[d][tj * 4];
#define DSTEP(c, KRC, KIC)                                    \
            { float dr = qr - KRC; float di = qi - KIC;       \
              acc[c] = fmaf(dr, dr, acc[c]);                  \
              acc[c] = fmaf(di, di, acc[c]); }
            DSTEP(0, kr.x, ki.x)
            DSTEP(1, kr.y, ki.y)
            DSTEP(2, kr.z, ki.z)
            DSTEP(3, kr.w, ki.w)
#undef DSTEP
        }

#pragma unroll
        for (int c = 0; c < 4; c++) {
            int j = j0 + tj * 4 + c;
            if (j <= i) {
                float t_j = tall[j] * invT;
                float dtt = fmaxf(t_i - t_j, 0.f);
                float x = dtt * den;
                float g = denok ? (expm1f(x) / den) : dtt;
                float Vv = om * g + ga * expf(x);
                float base = nf2 * Vv + m2i * acc[c];
                sP[ti][j] = -tau2 * logf(base);
            }
        }
    }
    __syncthreads();

    float mx = -1e30f;
    for (int j = tj; j <= i; j += 8) mx = fmaxf(mx, sP[ti][j]);
#pragma unroll
    for (int m = 1; m < 8; m <<= 1) mx = fmaxf(mx, __shfl_xor(mx, m));
    float sum = 0.f;
    for (int j = tj; j <= i; j += 8) {
        float e = expf(sP[ti][j] - mx);
        sP[ti][j] = e;
        sum += e;
    }
#pragma unroll
    for (int m = 1; m < 8; m <<= 1) sum += __shfl_xor(sum, m);
    const float inv = 1.f / sum;

    float* srow   = qij + ((b * 512 + i) * 256) * 8 + h;
    float* qi_out = qij + ((b * 512 + 256 + i) * 256) * 8 + h;
    const int jfill = i0 + 32;
    for (int j = tj; j < 256; j += 8) {
        float p = 0.f;
        if (j <= i) p = sP[ti][j] * inv;
        if (j < jfill) sP[ti][j] = p;
        srow[j * 8]   = p;
        qi_out[j * 8] = 0.f;
    }
    __syncthreads();

    const int dl = tid & 7;
    float accR[8] = {0.f}, accI[8] = {0.f};

    for (int jt = 0; jt <= it; jt++) {
        const int j0 = jt * 32;
        {
            const float* sr = uvr + ((b * 8 + h) * 256 + j0 + ti) * 64;
            const float* si = uvi + ((b * 8 + h) * 256 + j0 + ti) * 64;
            *(float4*)&sVr[ti][dl * 4]      = *(const float4*)&sr[dl * 4];
            *(float4*)&sVr[ti][32 + dl * 4] = *(const float4*)&sr[32 + dl * 4];
            *(float4*)&sVi[ti][dl * 4]      = *(const float4*)&si[dl * 4];
            *(float4*)&sVi[ti][32 + dl * 4] = *(const float4*)&si[32 + dl * 4];
        }
        __syncthreads();

#pragma unroll 8
        for (int jj = 0; jj < 32; jj++) {
            float a = sP[ti][j0 + jj];
            float4 v0 = *(float4*)&sVr[jj][dl * 8];
            float4 v1 = *(float4*)&sVr[jj][dl * 8 + 4];
            float4 w0 = *(float4*)&sVi[jj][dl * 8];
            float4 w1 = *(float4*)&sVi[jj][dl * 8 + 4];
            float vv[8] = {v0.x, v0.y, v0.z, v0.w, v1.x, v1.y, v1.z, v1.w};
            float ww[8] = {w0.x, w0.y, w0.z, w0.w, w1.x, w1.y, w1.z, w1.w};
#pragma unroll
            for (int c = 0; c < 8; c++) {
                accR[c] = fmaf(a, vv[c], accR[c]);
                accI[c] = fmaf(a, ww[c], accI[c]);
            }
        }
        __syncthreads();
    }

    const int cb = h * 64 + dl * 8;
    f32x4 fr0 = *(const f32x4*)&efr[i * 512 + cb];
    f32x4 fr1 = *(const f32x4*)&efr[i * 512 + cb + 4];
    f32x4 fi0 = *(const f32x4*)&efi[i * 512 + cb];
    f32x4 fi1 = *(const f32x4*)&efi[i * 512 + cb + 4];
    f32x4 mr0 = *(const f32x4*)&efr[cb];
    f32x4 mr1 = *(const f32x4*)&efr[cb + 4];
    f32x4 mi0 = *(const f32x4*)&efi[cb];
    f32x4 mi1 = *(const f32x4*)&efi[cb + 4];

    u16x8 o_r, o_i;
#pragma unroll
    for (int c = 0; c < 8; c++) {
        float fr = (c < 4) ? fr0[c] : fr1[c - 4];
        float fi = (c < 4) ? fi0[c] : fi1[c - 4];
        float mr = (c < 4) ? mr0[c] : mr1[c - 4];
        float mi = (c < 4) ? mi0[c] : mi1[c - 4];
        int p = dl * 64 + c * 8 + h;
        float estr = fr * accR[c] - fi * accI[c];
        float esti = fr * accI[c] + fi * accR[c];
        float et = sigm(ETA[p]);
        float w1 = 1.f - et;
        float w2 = sigm(et);
        float vr_ = vr[(b * 256 + i) * 512 + p];
        float vi_ = vi[(b * 256 + i) * 512 + p];
        float elr = w1 * vr_ + w2 * estr;
        float eli = w1 * vi_ + w2 * esti;
        out_est[((b * 2 + 0) * 256 + i) * 512 + p] = elr;
        out_est[((b * 2 + 1) * 256 + i) * 512 + p] = eli;
        o_r[c] = f2b(mr * elr - mi * eli);
        o_i[c] = f2b(mr * eli + mi * elr);
    }
    __hip_bfloat16* ap = a2p + (b * 256 + i) * 1024 + cb;
    *(u16x8*)ap         = o_r;
    *(u16x8*)(ap + 512) = o_i;
}

// ---------------------------------------------------------------------------
// Kernel 4 (launch B): blocks 0..63 = output projection (verified cmfma
// IS_P=true body); blocks 64..16447 = Z_ij b=1 half. cmfmaP's a2p input is
// ready (produced in launch A; stream-ordered).
// ---------------------------------------------------------------------------
__global__ __launch_bounds__(256) void k_zij_proj(
    const float* __restrict__ efr, const float* __restrict__ efi,
    const float* __restrict__ uvr, const float* __restrict__ uvi,
    float* __restrict__ zout,
    const __hip_bfloat16* __restrict__ bfbase,
    const __hip_bfloat16* __restrict__ a2p,
    const float* __restrict__ bp,
    float* __restrict__ outp)
{
    __shared__ __align__(16) char sm[24576];

    const int bid = blockIdx.x;
    const int tid = threadIdx.x;

    if (bid >= 64) {
        // ---------------- Z_ij path, b = 1 ----------------
        const int z  = bid - 64;
        const int j0 = (z & 63) * 4;
        const int i  = z >> 6;        // 0..255
        const int b  = 1;
#pragma unroll
        for (int half = 0; half < 2; half++) {
            int dt = half * 256 + tid;
            float fr = efr[i * 512 + dt];
            float fi = efi[i * 512 + dt];
            int h = dt >> 6, d = dt & 63;
            const float* ur = uvr + ((b * 8 + h) * 256) * 64 + d;
            const float* ui = uvi + ((b * 8 + h) * 256) * 64 + d;
#pragma unroll
            for (int jj = 0; jj < 4; jj++) {
                int j = j0 + jj;
                float vr_ = ur[j * 64];
                float vi_ = ui[j * 64];
                float zr = fr * vr_ - fi * vi_;
                float zi = fr * vi_ + fi * vr_;
                int idx0 = (b * 2) * 33554432 + i * 131072 + j * 512 + dt;
                __builtin_nontemporal_store(zr, &zout[idx0]);
                __builtin_nontemporal_store(zi, &zout[idx0 + 33554432]);
            }
        }
        return;
    }

    // ---------------- output projection path (cmfma IS_P=true) ----------------
    char* sA  = sm;
    char* sBr = sm + 8192;
    char* sBi = sm + 16384;

    const __hip_bfloat16* A2 = a2p;
    const __hip_bfloat16* Br = bfbase + B2R0 + 3 * 1048576;
    const __hip_bfloat16* Bi = Br + 524288;

    const int m0 = (bid >> 3) * 64;
    const int n0 = (bid & 7) * 64;
    const int lane = tid & 63;
    const int wv2 = tid >> 6;
    const int wr = wv2 >> 1, wc = wv2 & 1;
    const int lx = lane & 15, lhi = lane >> 4;

    const int srow  = tid >> 2;
    const int sslot = (tid & 3) * 32;

    const char* gA  = (const char*)(A2 + (size_t)(m0 + srow) * 1024);
    const char* gBr = (const char*)(Br + (size_t)(n0 + srow) * 1024);
    const char* gBi = (const char*)(Bi + (size_t)(n0 + srow) * 1024);
    const int swz = (srow & 7) << 4;
    char* dA  = sA  + srow * 128;
    char* dBr = sBr + srow * 128;
    char* dBi = sBi + srow * 128;

    f32x4 accR[2][2] = {};
    f32x4 accI[2][2] = {};

    int rowA[2], rowB[2];
    rowA[0] = wr * 32 + lx;  rowA[1] = rowA[0] + 16;
    rowB[0] = wc * 32 + lx;  rowB[1] = rowB[0] + 16;

    for (int kt = 0; kt < 16; ++kt) {
        const int kb = kt * 128;
        {
            float4 a0 = *(const float4*)(gA  + kb + sslot);
            float4 a1 = *(const float4*)(gA  + kb + sslot + 16);
            float4 b0 = *(const float4*)(gBr + kb + sslot);
            float4 b1 = *(const float4*)(gBr + kb + sslot + 16);
            float4 c0 = *(const float4*)(gBi + kb + sslot);
            float4 c1 = *(const float4*)(gBi + kb + sslot + 16);
            *(float4*)(dA  + ( sslot       ^ swz)) = a0;
            *(float4*)(dA  + ((sslot + 16) ^ swz)) = a1;
            *(float4*)(dBr + ( sslot       ^ swz)) = b0;
            *(float4*)(dBr + ((sslot + 16) ^ swz)) = b1;
            *(float4*)(dBi + ( sslot       ^ swz)) = c0;
            *(float4*)(dBi + ((sslot + 16) ^ swz)) = c1;
        }
        __syncthreads();
#pragma unroll
        for (int kk = 0; kk < 2; ++kk) {
            const int kbyte = kk * 64 + lhi * 16;
            bf16x8 af[2], brf[2], bif[2];
#pragma unroll
            for (int x = 0; x < 2; ++x) {
                int ra = rowA[x];
                af[x]  = *(const bf16x8*)(sA  + ra * 128 + (kbyte ^ ((ra & 7) << 4)));
                int rb = rowB[x];
                brf[x] = *(const bf16x8*)(sBr + rb * 128 + (kbyte ^ ((rb & 7) << 4)));
                bif[x] = *(const bf16x8*)(sBi + rb * 128 + (kbyte ^ ((rb & 7) << 4)));
            }
#pragma unroll
            for (int a = 0; a < 2; ++a)
#pragma unroll
                for (int bb = 0; bb < 2; ++bb) {
                    accR[a][bb] = __builtin_amdgcn_mfma_f32_16x16x32_bf16(
                        af[a], brf[bb], accR[a][bb], 0, 0, 0);
                    accI[a][bb] = __builtin_amdgcn_mfma_f32_16x16x32_bf16(
                        af[a], bif[bb], accI[a][bb], 0, 0, 0);
                }
        }
        __syncthreads();
    }

#pragma unroll
    for (int a = 0; a < 2; ++a) {
#pragma unroll
        for (int bb = 0; bb < 2; ++bb) {
#pragma unroll
            for (int j = 0; j < 4; ++j) {
                int m = m0 + wr * 32 + a * 16 + lhi * 4 + j;
                int n = n0 + wc * 32 + bb * 16 + lx;
                float yr = accR[a][bb][j] + bp[n];
                float yi = accI[a][bb][j] + bp[512 + n];
                int b = m >> 8;
                int rowo = m * 512 + b * 131072;
                outp[rowo + n] = yr;
                outp[rowo + 131072 + n] = yi;
            }
        }
    }
}

// ---------------------------------------------------------------------------
extern "C" void kernel_launch(void* const* d_in, const int* in_sizes, int n_in,
                              void* d_out, int out_size, void* d_ws, size_t ws_size,
                              hipStream_t stream)
{
    const float* Zq   = (const float*)d_in[0];
    const float* Zk   = (const float*)d_in[1];
    const float* Zv   = (const float*)d_in[2];
    const float* tall = (const float*)d_in[3];
    const float* Wq   = (const float*)d_in[4];
    const float* bq   = (const float*)d_in[5];
    const float* Wk   = (const float*)d_in[6];
    const float* bk   = (const float*)d_in[7];
    const float* Wv   = (const float*)d_in[8];
    const float* bv   = (const float*)d_in[9];
    const float* Wp   = (const float*)d_in[10];
    const float* bp   = (const float*)d_in[11];
    const float* Lim  = (const float*)d_in[12];
    const float* Lre  = (const float*)d_in[13];
    const float* Lom  = (const float*)d_in[14];
    const float* Lga  = (const float*)d_in[15];
    const float* NF   = (const float*)d_in[16];
    const float* TAU  = (const float*)d_in[17];
    const float* ETA  = (const float*)d_in[18];

    float* out = (float*)d_out;
    float* ws  = (float*)d_ws;

    float* efr = ws + WS_EFR; float* efi = ws + WS_EFI;
    float* ebr = ws + WS_EBR; float* ebi = ws + WS_EBI;
    float* uqr = ws + WS_UQR; float* uqi = ws + WS_UQI;
    float* ukr = ws + WS_UKR; float* uki = ws + WS_UKI;
    float* uvr = ws + WS_UVR; float* uvi = ws + WS_UVI;
    float* vr  = ws + WS_VR;  float* vi  = ws + WS_VI;
    __hip_bfloat16* bfbase = (__hip_bfloat16*)(ws + WS_BF);
    __hip_bfloat16* a2p    = (__hip_bfloat16*)(ws + WS_EBR);  // reuse eb region

    k_prep<<<1792, 256, 0, stream>>>(tall, Lim, Lre, Zq, Zk, Zv,
                                     Wq, Wk, Wv, Wp,
                                     efr, efi, ebr, ebi,
                                     out + OFF_EPO, bfbase);

    k_cmfma_qkv<<<dim3(8, 8, 3), 256, 0, stream>>>(
        bfbase, bq, bk, bv, ebr, ebi,
        uqr, uqi, ukr, uki, uvr, uvi, vr, vi);

    k_zij_attn<<<16512, 256, 0, stream>>>(
        efr, efi, uvr, uvi, out + OFF_ZIJ,
        uqr, uqi, ukr, uki, tall, Lre, Lom, Lga, NF, TAU,
        out + OFF_QIJ, vr, vi, ETA, out + OFF_EST, a2p);

    k_zij_proj<<<16448, 256, 0, stream>>>(
        efr, efi, uvr, uvi, out + OFF_ZIJ,
        bfbase, a2p, bp, out + OFF_OUT);
}

// Round 11
// 138.894 us; speedup vs baseline: 1.1178x; 1.1178x over previous
//
#include <hip/hip_runtime.h>
#include <hip/hip_bf16.h>
#include <math.h>

// Problem constants
constexpr int kB  = 2;
constexpr int kS  = 256;
constexpr int kH  = 8;
constexpr float kEPS = 1e-5f;

// Output offsets (floats) in d_out, in reference return order
constexpr int OFF_EST = 0;                         // (B,2,S,DV,H)   524288
constexpr int OFF_OUT = 524288;                    // (B,2,S,DE)     524288
constexpr int OFF_QIJ = 1048576;                   // (B,2,S,S,H)    2097152
constexpr int OFF_ZIJ = 3145728;                   // (B,2,S,S,DT)   134217728
constexpr int OFF_EPO = 137363456;                 // (2,512,1)      1024

// Workspace offsets (floats)
constexpr int WS_EFR = 0;          // (S,DT)
constexpr int WS_EFI = 131072;
constexpr int WS_EBR = 262144;     // reused later as A2P (bf16, 1 MB spans EBR+EBI)
constexpr int WS_EBI = 393216;
constexpr int WS_UQR = 524288;     // (B,H,S,DV)
constexpr int WS_UQI = 786432;
constexpr int WS_UKR = 1048576;    // (B,H,DV,S)  transposed
constexpr int WS_UKI = 1310720;
constexpr int WS_UVR = 1572864;    // (B,H,S,DV)
constexpr int WS_UVI = 1835008;
constexpr int WS_VR  = 2097152;    // (B,S,DV,H)
constexpr int WS_VI  = 2359296;
constexpr int WS_BF  = 3145728;    // bf16 region base (float offset)

// bf16-element offsets within bf16 region
constexpr int A2Q = 0;             // [512][1024]
constexpr int A2K = 524288;
constexpr int A2V = 1048576;
constexpr int B2R0 = 1572864;      // B2R(z) = B2R0 + z*1048576; B2I = +524288

typedef __attribute__((ext_vector_type(8))) short bf16x8;
typedef __attribute__((ext_vector_type(4))) float f32x4;
typedef __attribute__((ext_vector_type(8))) unsigned short u16x8;
typedef __attribute__((ext_vector_type(4))) unsigned short u16x4;

__device__ __forceinline__ float sigm(float x) { return 1.f / (1.f + expf(-x)); }
__device__ __forceinline__ unsigned short f2b(float f) {
    __hip_bfloat16 h = __float2bfloat16(f);
    return *reinterpret_cast<unsigned short*>(&h);
}

// ---------------------------------------------------------------------------
// Kernel 1 (fused prep): blocks 0..511 ef/eb+epoch, 512..1279 convA,
// 1280..1791 convW.
// ---------------------------------------------------------------------------
__global__ __launch_bounds__(256) void k_prep(
    const float* __restrict__ tall, const float* __restrict__ Lim,
    const float* __restrict__ Lre,
    const float* __restrict__ zq, const float* __restrict__ zk,
    const float* __restrict__ zv,
    const float* __restrict__ wq, const float* __restrict__ wk,
    const float* __restrict__ wv, const float* __restrict__ wp,
    float* __restrict__ efr, float* __restrict__ efi,
    float* __restrict__ ebr, float* __restrict__ ebi,
    float* __restrict__ epo, __hip_bfloat16* __restrict__ bfbase)
{
    __shared__ float s0[64][65];
    __shared__ float s1[64][65];
    const int bid = blockIdx.x;
    const int tid = threadIdx.x;

    if (bid < 512) {
        // ---- ef/eb precompute ----
        int idx = bid * 256 + tid;
        int s = idx >> 9;
        int c = idx & 511;
        int h = c >> 6;
        int d = c & 63;
        float li = (d < 32) ? Lim[h * 32 + d] : -Lim[h * 32 + d - 32];
        float lr = Lre[h];
        float t  = tall[s] / (tall[kS - 1] - tall[0]);
        float ph  = t * li;
        float mag = expf(t * lr);
        float cp  = cosf(ph);
        float sp  = sinf(ph);
        efr[idx] = mag * cp;
        efi[idx] = mag * sp;
        ebr[idx] = cp / mag;
        ebi[idx] = -sp / mag;
        if (s == 0) {
            epo[c]       = lr;
            epo[512 + c] = li;
        }
    } else if (bid < 1280) {
        // ---- convA: Zq/Zk/Zv -> bf16 [512][1024] ----
        int idx = (bid - 512) * 256 + tid;
        int tz  = idx >> 16;
        int rem = idx & 65535;
        int m   = rem >> 7;
        int k0  = (rem & 127) * 8;
        const float* src = (tz == 0) ? zq : (tz == 1) ? zk : zv;
        int b = m >> 8, s = m & 255;
        int c = (k0 >= 512) ? 1 : 0;
        int e = k0 - c * 512;
        const float* p = src + ((b * 2 + c) * 256 + s) * 512 + e;
        float4 v0 = *(const float4*)p;
        float4 v1 = *(const float4*)(p + 4);
        u16x8 o;
        o[0] = f2b(v0.x); o[1] = f2b(v0.y); o[2] = f2b(v0.z); o[3] = f2b(v0.w);
        o[4] = f2b(v1.x); o[5] = f2b(v1.y); o[6] = f2b(v1.z); o[7] = f2b(v1.w);
        __hip_bfloat16* dst = bfbase + ((tz == 0) ? A2Q : (tz == 1) ? A2K : A2V)
                              + m * 1024 + k0;
        *(u16x8*)dst = o;
    } else {
        // ---- convW: weights -> bf16 [512 n][1024 k] transposed ----
        int wid = bid - 1280;
        int z = wid >> 7;
        int r2 = wid & 127;
        int k0 = (r2 & 15) * 64;
        int n0 = (r2 >> 4) * 64;
        const float* W  = (z == 0) ? wq : (z == 1) ? wk : (z == 2) ? wv : wp;
        const float* W0 = W;
        const float* W1 = W + 262144;
        const int kp = k0 & 511;
        const bool hf = (k0 >= 512);
        const int r = tid >> 2;
        const int q = tid & 3;
#pragma unroll
        for (int c = 0; c < 4; ++c) {
            int col = q * 16 + c * 4;
            *(float4*)&s0[r][col] = *(const float4*)&W0[(kp + r) * 512 + n0 + col];
            *(float4*)&s1[r][col] = *(const float4*)&W1[(kp + r) * 512 + n0 + col];
        }
        __syncthreads();
        u16x8 r0, r1, i0, i1;
#pragma unroll
        for (int u = 0; u < 8; ++u) {
            int kl = q * 16 + u;
            float w0 = s0[kl][r], w1 = s1[kl][r];
            r0[u] = f2b(hf ? -w1 : w0);
            i0[u] = f2b(hf ?  w0 : w1);
        }
#pragma unroll
        for (int u = 0; u < 8; ++u) {
            int kl = q * 16 + 8 + u;
            float w0 = s0[kl][r], w1 = s1[kl][r];
            r1[u] = f2b(hf ? -w1 : w0);
            i1[u] = f2b(hf ?  w0 : w1);
        }
        __hip_bfloat16* pr = bfbase + B2R0 + z * 1048576
                             + (size_t)(n0 + r) * 1024 + k0 + q * 16;
        __hip_bfloat16* pi = pr + 524288;
        *(u16x8*)pr       = r0;
        *(u16x8*)(pr + 8) = r1;
        *(u16x8*)pi       = i0;
        *(u16x8*)(pi + 8) = i1;
    }
}

// ---------------------------------------------------------------------------
// Kernel 2: MFMA complex GEMM (verified round-2/6 kernel, unchanged)
// ---------------------------------------------------------------------------
template<bool IS_P>
__global__ __launch_bounds__(256) void k_cmfma(
    const __hip_bfloat16* __restrict__ bfbase,
    const __hip_bfloat16* __restrict__ a2p,
    const float* __restrict__ bq, const float* __restrict__ bk,
    const float* __restrict__ bv, const float* __restrict__ bp,
    const float* __restrict__ ebr, const float* __restrict__ ebi,
    float* __restrict__ uqr, float* __restrict__ uqi,
    float* __restrict__ ukr, float* __restrict__ uki,
    float* __restrict__ uvr, float* __restrict__ uvi,
    float* __restrict__ vr,  float* __restrict__ vi,
    float* __restrict__ outp)
{
    __shared__ __align__(16) char sm[24576];
    char* sA  = sm;
    char* sBr = sm + 8192;
    char* sBi = sm + 16384;

    const int mode = IS_P ? 3 : (int)blockIdx.z;
    const __hip_bfloat16* A2 = IS_P ? a2p
        : bfbase + ((mode == 0) ? A2Q : (mode == 1) ? A2K : A2V);
    const __hip_bfloat16* Br = bfbase + B2R0 + mode * 1048576;
    const __hip_bfloat16* Bi = Br + 524288;
    const float* bias = IS_P ? bp : ((mode == 0) ? bq : (mode == 1) ? bk : bv);

    const int tid = threadIdx.x;
    const int m0 = blockIdx.y * 64;
    const int n0 = blockIdx.x * 64;
    const int lane = tid & 63;
    const int wv2 = tid >> 6;
    const int wr = wv2 >> 1, wc = wv2 & 1;
    const int lx = lane & 15, lhi = lane >> 4;

    const int srow  = tid >> 2;
    const int sslot = (tid & 3) * 32;

    const char* gA  = (const char*)(A2 + (size_t)(m0 + srow) * 1024);
    const char* gBr = (const char*)(Br + (size_t)(n0 + srow) * 1024);
    const char* gBi = (const char*)(Bi + (size_t)(n0 + srow) * 1024);
    const int swz = (srow & 7) << 4;
    char* dA  = sA  + srow * 128;
    char* dBr = sBr + srow * 128;
    char* dBi = sBi + srow * 128;

    f32x4 accR[2][2] = {};
    f32x4 accI[2][2] = {};

    int rowA[2], rowB[2];
    rowA[0] = wr * 32 + lx;  rowA[1] = rowA[0] + 16;
    rowB[0] = wc * 32 + lx;  rowB[1] = rowB[0] + 16;

    for (int kt = 0; kt < 16; ++kt) {
        const int kb = kt * 128;
        {
            float4 a0 = *(const float4*)(gA  + kb + sslot);
            float4 a1 = *(const float4*)(gA  + kb + sslot + 16);
            float4 b0 = *(const float4*)(gBr + kb + sslot);
            float4 b1 = *(const float4*)(gBr + kb + sslot + 16);
            float4 c0 = *(const float4*)(gBi + kb + sslot);
            float4 c1 = *(const float4*)(gBi + kb + sslot + 16);
            *(float4*)(dA  + ( sslot       ^ swz)) = a0;
            *(float4*)(dA  + ((sslot + 16) ^ swz)) = a1;
            *(float4*)(dBr + ( sslot       ^ swz)) = b0;
            *(float4*)(dBr + ((sslot + 16) ^ swz)) = b1;
            *(float4*)(dBi + ( sslot       ^ swz)) = c0;
            *(float4*)(dBi + ((sslot + 16) ^ swz)) = c1;
        }
        __syncthreads();
#pragma unroll
        for (int kk = 0; kk < 2; ++kk) {
            const int kbyte = kk * 64 + lhi * 16;
            bf16x8 af[2], brf[2], bif[2];
#pragma unroll
            for (int x = 0; x < 2; ++x) {
                int ra = rowA[x];
                af[x]  = *(const bf16x8*)(sA  + ra * 128 + (kbyte ^ ((ra & 7) << 4)));
                int rb = rowB[x];
                brf[x] = *(const bf16x8*)(sBr + rb * 128 + (kbyte ^ ((rb & 7) << 4)));
                bif[x] = *(const bf16x8*)(sBi + rb * 128 + (kbyte ^ ((rb & 7) << 4)));
            }
#pragma unroll
            for (int a = 0; a < 2; ++a)
#pragma unroll
                for (int bb = 0; bb < 2; ++bb) {
                    accR[a][bb] = __builtin_amdgcn_mfma_f32_16x16x32_bf16(
                        af[a], brf[bb], accR[a][bb], 0, 0, 0);
                    accI[a][bb] = __builtin_amdgcn_mfma_f32_16x16x32_bf16(
                        af[a], bif[bb], accI[a][bb], 0, 0, 0);
                }
        }
        __syncthreads();
    }

#pragma unroll
    for (int a = 0; a < 2; ++a) {
#pragma unroll
        for (int bb = 0; bb < 2; ++bb) {
#pragma unroll
            for (int j = 0; j < 4; ++j) {
                int m = m0 + wr * 32 + a * 16 + lhi * 4 + j;
                int n = n0 + wc * 32 + bb * 16 + lx;
                float yr = accR[a][bb][j] + bias[n];
                float yi = accI[a][bb][j] + bias[512 + n];
                int b = m >> 8, s = m & 255;
                if (IS_P) {
                    int rowo = m * 512 + b * 131072;
                    outp[rowo + n] = yr;
                    outp[rowo + 131072 + n] = yi;
                } else {
                    int h = n >> 6, d = n & 63;
                    float er_ = ebr[s * 512 + n], ei_ = ebi[s * 512 + n];
                    float ur = er_ * yr - ei_ * yi;
                    float ui = er_ * yi + ei_ * yr;
                    if (mode == 0) {
                        int idx = ((b * 8 + h) * 256 + s) * 64 + d;
                        uqr[idx] = ur; uqi[idx] = ui;
                    } else if (mode == 1) {
                        int idx = ((b * 8 + h) * 64 + d) * 256 + s;
                        ukr[idx] = ur; uki[idx] = ui;
                    } else {
                        int idx = ((b * 8 + h) * 256 + s) * 64 + d;
                        uvr[idx] = ur; uvi[idx] = ui;
                        int vidx = (b * 256 + s) * 512 + d * 8 + h;
                        vr[vidx] = yr; vi[vidx] = yi;
                    }
                }
            }
        }
    }
}

// ---------------------------------------------------------------------------
// Kernel 3 (merged launch, round-9 verified): blocks 0..127 =
// scores+softmax+PV+est; blocks 128..32895 = Z_ij streaming write.
// ---------------------------------------------------------------------------
__global__ __launch_bounds__(256) void k_zij_attn(
    const float* __restrict__ efr, const float* __restrict__ efi,
    const float* __restrict__ uvr, const float* __restrict__ uvi,
    float* __restrict__ zout,
    const float* __restrict__ uqr, const float* __restrict__ uqi,
    const float* __restrict__ ukr, const float* __restrict__ uki,
    const float* __restrict__ tall,
    const float* __restrict__ Lre, const float* __restrict__ Lom,
    const float* __restrict__ Lga, const float* __restrict__ NF,
    const float* __restrict__ TAU,
    float* __restrict__ qij,
    const float* __restrict__ vr,  const float* __restrict__ vi,
    const float* __restrict__ ETA,
    float* __restrict__ out_est, __hip_bfloat16* __restrict__ a2p)
{
    __shared__ __align__(16) char smem[66688];
    float (*sP)[257] = (float(*)[257])smem;
    float (*sKr)[32] = (float(*)[32])(smem + 32896);
    float (*sKi)[32] = (float(*)[32])(smem + 41088);
    float (*sQr)[68] = (float(*)[68])(smem + 49280);
    float (*sQi)[68] = (float(*)[68])(smem + 57984);
    float (*sVr)[64] = (float(*)[64])(smem + 32896);
    float (*sVi)[64] = (float(*)[64])(smem + 41088);

    const int bid = blockIdx.x;
    const int tid = threadIdx.x;

    if (bid >= 128) {
        // ---------------- Z_ij path ----------------
        const int z  = bid - 128;
        const int j0 = (z & 63) * 4;
        const int i  = (z >> 6) & 255;
        const int b  = z >> 14;
#pragma unroll
        for (int half = 0; half < 2; half++) {
            int dt = half * 256 + tid;
            float fr = efr[i * 512 + dt];
            float fi = efi[i * 512 + dt];
            int h = dt >> 6, d = dt & 63;
            const float* ur = uvr + ((b * 8 + h) * 256) * 64 + d;
            const float* ui = uvi + ((b * 8 + h) * 256) * 64 + d;
#pragma unroll
            for (int jj = 0; jj < 4; jj++) {
                int j = j0 + jj;
                float vr_ = ur[j * 64];
                float vi_ = ui[j * 64];
                float zr = fr * vr_ - fi * vi_;
                float zi = fr * vi_ + fi * vr_;
                int idx0 = (b * 2) * 33554432 + i * 131072 + j * 512 + dt;
                __builtin_nontemporal_store(zr, &zout[idx0]);
                __builtin_nontemporal_store(zi, &zout[idx0 + 33554432]);
            }
        }
        return;
    }

    // ------------- attn path: scores + softmax + PV + est -------------
    const int it = bid & 7;
    const int h  = (bid >> 3) & 7;
    const int b  = bid >> 6;
    const int i0 = it * 32;
    const int ti = tid >> 3;
    const int tj = tid & 7;
    const int i  = i0 + ti;

    {
        const float* qsr = uqr + ((b * 8 + h) * 256 + i) * 64;
        const float* qsi = uqi + ((b * 8 + h) * 256 + i) * 64;
        *(float4*)&sQr[ti][tj * 4]      = *(const float4*)&qsr[tj * 4];
        *(float4*)&sQr[ti][32 + tj * 4] = *(const float4*)&qsr[32 + tj * 4];
        *(float4*)&sQi[ti][tj * 4]      = *(const float4*)&qsi[tj * 4];
        *(float4*)&sQi[ti][32 + tj * 4] = *(const float4*)&qsi[32 + tj * 4];
    }

    const float lre  = Lre[h];
    const float om   = Lom[h] * Lom[h];
    const float ga   = Lga[h] * Lga[h] + kEPS;
    const float nf2  = NF[h] * NF[h] + kEPS;
    const float tau2 = TAU[h] * TAU[h];
    const float den  = 2.f * lre;
    const float invT = 1.f / (tall[kS - 1] - tall[0]);
    const float t_i  = tall[i] * invT;
    const float m2i  = expf(2.f * t_i * lre);
    const bool  denok = fabsf(den) > 1e-6f;

    const int kr2 = tid >> 2;
    const int kq2 = tid & 3;

    for (int jt = 0; jt <= it; ++jt) {
        const int j0 = jt * 32;
        __syncthreads();
        {
            const float* ksrc_r = ukr + ((b * 8 + h) * 64 + kr2) * 256 + j0;
            const float* ksrc_i = uki + ((b * 8 + h) * 64 + kr2) * 256 + j0;
            *(float4*)&sKr[kr2][kq2 * 4]      = *(const float4*)&ksrc_r[kq2 * 4];
            *(float4*)&sKr[kr2][16 + kq2 * 4] = *(const float4*)&ksrc_r[16 + kq2 * 4];
            *(float4*)&sKi[kr2][kq2 * 4]      = *(const float4*)&ksrc_i[kq2 * 4];
            *(float4*)&sKi[kr2][16 + kq2 * 4] = *(const float4*)&ksrc_i[16 + kq2 * 4];
        }
        __syncthreads();

        float acc[4] = {0.f, 0.f, 0.f, 0.f};
#pragma unroll 16
        for (int d = 0; d < 64; d++) {
            float qr = sQr[ti][d];
            float qi = sQi[ti][d];
            float4 kr = *(float4*)&sKr[d][tj * 4];
            float4 ki = *(float4*)&sKi[d][tj * 4];
#define DSTEP(c, KRC, KIC)                                    \
            { float dr = qr - KRC; float di = qi - KIC;       \
              acc[c] = fmaf(dr, dr, acc[c]);                  \
              acc[c] = fmaf(di, di, acc[c]); }
            DSTEP(0, kr.x, ki.x)
            DSTEP(1, kr.y, ki.y)
            DSTEP(2, kr.z, ki.z)
            DSTEP(3, kr.w, ki.w)
#undef DSTEP
        }

#pragma unroll
        for (int c = 0; c < 4; c++) {
            int j = j0 + tj * 4 + c;
            if (j <= i) {
                float t_j = tall[j] * invT;
                float dtt = fmaxf(t_i - t_j, 0.f);
                float x = dtt * den;
                float g = denok ? (expm1f(x) / den) : dtt;
                float Vv = om * g + ga * expf(x);
                float base = nf2 * Vv + m2i * acc[c];
                sP[ti][j] = -tau2 * logf(base);
            }
        }
    }
    __syncthreads();

    float mx = -1e30f;
    for (int j = tj; j <= i; j += 8) mx = fmaxf(mx, sP[ti][j]);
#pragma unroll
    for (int m = 1; m < 8; m <<= 1) mx = fmaxf(mx, __shfl_xor(mx, m));
    float sum = 0.f;
    for (int j = tj; j <= i; j += 8) {
        float e = expf(sP[ti][j] - mx);
        sP[ti][j] = e;
        sum += e;
    }
#pragma unroll
    for (int m = 1; m < 8; m <<= 1) sum += __shfl_xor(sum, m);
    const float inv = 1.f / sum;

    float* srow   = qij + ((b * 512 + i) * 256) * 8 + h;
    float* qi_out = qij + ((b * 512 + 256 + i) * 256) * 8 + h;
    const int jfill = i0 + 32;
    for (int j = tj; j < 256; j += 8) {
        float p = 0.f;
        if (j <= i) p = sP[ti][j] * inv;
        if (j < jfill) sP[ti][j] = p;
        srow[j * 8]   = p;
        qi_out[j * 8] = 0.f;
    }
    __syncthreads();

    const int dl = tid & 7;
    float accR[8] = {0.f}, accI[8] = {0.f};

    for (int jt = 0; jt <= it; jt++) {
        const int j0 = jt * 32;
        {
            const float* sr = uvr + ((b * 8 + h) * 256 + j0 + ti) * 64;
            const float* si = uvi + ((b * 8 + h) * 256 + j0 + ti) * 64;
            *(float4*)&sVr[ti][dl * 4]      = *(const float4*)&sr[dl * 4];
            *(float4*)&sVr[ti][32 + dl * 4] = *(const float4*)&sr[32 + dl * 4];
            *(float4*)&sVi[ti][dl * 4]      = *(const float4*)&si[dl * 4];
            *(float4*)&sVi[ti][32 + dl * 4] = *(const float4*)&si[32 + dl * 4];
        }
        __syncthreads();

#pragma unroll 8
        for (int jj = 0; jj < 32; jj++) {
            float a = sP[ti][j0 + jj];
            float4 v0 = *(float4*)&sVr[jj][dl * 8];
            float4 v1 = *(float4*)&sVr[jj][dl * 8 + 4];
            float4 w0 = *(float4*)&sVi[jj][dl * 8];
            float4 w1 = *(float4*)&sVi[jj][dl * 8 + 4];
            float vv[8] = {v0.x, v0.y, v0.z, v0.w, v1.x, v1.y, v1.z, v1.w};
            float ww[8] = {w0.x, w0.y, w0.z, w0.w, w1.x, w1.y, w1.z, w1.w};
#pragma unroll
            for (int c = 0; c < 8; c++) {
                accR[c] = fmaf(a, vv[c], accR[c]);
                accI[c] = fmaf(a, ww[c], accI[c]);
            }
        }
        __syncthreads();
    }

    const int cb = h * 64 + dl * 8;
    f32x4 fr0 = *(const f32x4*)&efr[i * 512 + cb];
    f32x4 fr1 = *(const f32x4*)&efr[i * 512 + cb + 4];
    f32x4 fi0 = *(const f32x4*)&efi[i * 512 + cb];
    f32x4 fi1 = *(const f32x4*)&efi[i * 512 + cb + 4];
    f32x4 mr0 = *(const f32x4*)&efr[cb];
    f32x4 mr1 = *(const f32x4*)&efr[cb + 4];
    f32x4 mi0 = *(const f32x4*)&efi[cb];
    f32x4 mi1 = *(const f32x4*)&efi[cb + 4];

    u16x8 o_r, o_i;
#pragma unroll
    for (int c = 0; c < 8; c++) {
        float fr = (c < 4) ? fr0[c] : fr1[c - 4];
        float fi = (c < 4) ? fi0[c] : fi1[c - 4];
        float mr = (c < 4) ? mr0[c] : mr1[c - 4];
        float mi = (c < 4) ? mi0[c] : mi1[c - 4];
        int p = dl * 64 + c * 8 + h;
        float estr = fr * accR[c] - fi * accI[c];
        float esti = fr * accI[c] + fi * accR[c];
        float et = sigm(ETA[p]);
        float w1 = 1.f - et;
        float w2 = sigm(et);
        float vr_ = vr[(b * 256 + i) * 512 + p];
        float vi_ = vi[(b * 256 + i) * 512 + p];
        float elr = w1 * vr_ + w2 * estr;
        float eli = w1 * vi_ + w2 * esti;
        out_est[((b * 2 + 0) * 256 + i) * 512 + p] = elr;
        out_est[((b * 2 + 1) * 256 + i) * 512 + p] = eli;
        o_r[c] = f2b(mr * elr - mi * eli);
        o_i[c] = f2b(mr * eli + mi * elr);
    }
    __hip_bfloat16* ap = a2p + (b * 256 + i) * 1024 + cb;
    *(u16x8*)ap         = o_r;
    *(u16x8*)(ap + 512) = o_i;
}

// ---------------------------------------------------------------------------
extern "C" void kernel_launch(void* const* d_in, const int* in_sizes, int n_in,
                              void* d_out, int out_size, void* d_ws, size_t ws_size,
                              hipStream_t stream)
{
    const float* Zq   = (const float*)d_in[0];
    const float* Zk   = (const float*)d_in[1];
    const float* Zv   = (const float*)d_in[2];
    const float* tall = (const float*)d_in[3];
    const float* Wq   = (const float*)d_in[4];
    const float* bq   = (const float*)d_in[5];
    const float* Wk   = (const float*)d_in[6];
    const float* bk   = (const float*)d_in[7];
    const float* Wv   = (const float*)d_in[8];
    const float* bv   = (const float*)d_in[9];
    const float* Wp   = (const float*)d_in[10];
    const float* bp   = (const float*)d_in[11];
    const float* Lim  = (const float*)d_in[12];
    const float* Lre  = (const float*)d_in[13];
    const float* Lom  = (const float*)d_in[14];
    const float* Lga  = (const float*)d_in[15];
    const float* NF   = (const float*)d_in[16];
    const float* TAU  = (const float*)d_in[17];
    const float* ETA  = (const float*)d_in[18];

    float* out = (float*)d_out;
    float* ws  = (float*)d_ws;

    float* efr = ws + WS_EFR; float* efi = ws + WS_EFI;
    float* ebr = ws + WS_EBR; float* ebi = ws + WS_EBI;
    float* uqr = ws + WS_UQR; float* uqi = ws + WS_UQI;
    float* ukr = ws + WS_UKR; float* uki = ws + WS_UKI;
    float* uvr = ws + WS_UVR; float* uvi = ws + WS_UVI;
    float* vr  = ws + WS_VR;  float* vi  = ws + WS_VI;
    __hip_bfloat16* bfbase = (__hip_bfloat16*)(ws + WS_BF);
    __hip_bfloat16* a2p    = (__hip_bfloat16*)(ws + WS_EBR);  // reuse eb region

    k_prep<<<1792, 256, 0, stream>>>(tall, Lim, Lre, Zq, Zk, Zv,
                                     Wq, Wk, Wv, Wp,
                                     efr, efi, ebr, ebi,
                                     out + OFF_EPO, bfbase);

    k_cmfma<false><<<dim3(8, 8, 3), 256, 0, stream>>>(
        bfbase, nullptr, bq, bk, bv, bp, ebr, ebi,
        uqr, uqi, ukr, uki, uvr, uvi, vr, vi, nullptr);

    k_zij_attn<<<32896, 256, 0, stream>>>(
        efr, efi, uvr, uvi, out + OFF_ZIJ,
        uqr, uqi, ukr, uki, tall, Lre, Lom, Lga, NF, TAU,
        out + OFF_QIJ, vr, vi, ETA, out + OFF_EST, a2p);

    k_cmfma<true><<<dim3(8, 8, 1), 256, 0, stream>>>(
        bfbase, a2p, bq, bk, bv, bp, ebr, ebi,
        nullptr, nullptr, nullptr, nullptr, nullptr, nullptr, nullptr, nullptr,
        out + OFF_OUT);
}